// Round 1
// baseline (669.862 us; speedup 1.0000x reference)
//
#include <hip/hip_runtime.h>
#include <hip/hip_bf16.h>

// Problem constants
#define B_  16
#define S_  2048
#define C_  256
#define QK_ 256
#define H_  8
#define N_  512
#define D_  32
// SCALING = QK^-0.5 = 0.0625, folded into q projection epilogue.

typedef short  bf16x8 __attribute__((ext_vector_type(8)));
typedef float  f32x4  __attribute__((ext_vector_type(4)));

__device__ __forceinline__ unsigned short f2bf(float f) {
    union { float f; unsigned u; } v; v.f = f;
    unsigned r = v.u + 0x7fffu + ((v.u >> 16) & 1u);   // RNE
    return (unsigned short)(r >> 16);
}

// ---- K0: x (fp32, B*S x C) -> bf16, same layout --------------------------
__global__ void k_convert_x(const float* __restrict__ x,
                            unsigned short* __restrict__ xbf) {
    int i = blockIdx.x * blockDim.x + threadIdx.x;     // 0 .. 2097151 (float4s)
    float4 v = ((const float4*)x)[i];
    ushort4 o;
    o.x = f2bf(v.x); o.y = f2bf(v.y); o.z = f2bf(v.z); o.w = f2bf(v.w);
    ((ushort4*)xbf)[i] = o;
}

// ---- K1: WqT[n][c] = bf16(Wq[c][n])  (256x256, tiny) ---------------------
__global__ void k_wqt(const float* __restrict__ Wq,
                      unsigned short* __restrict__ wqt) {
    int n = blockIdx.x, c = threadIdx.x;
    wqt[n * 256 + c] = f2bf(Wq[c * 256 + n]);
}

// ---- K2: k proj: kbf[h][n][d] = bf16( env[n,:] . Wk[:, h*32+d] ) ---------
__global__ void k_kproj(const float* __restrict__ env,
                        const float* __restrict__ Wk,
                        unsigned short* __restrict__ kbf) {
    __shared__ float erow[256];
    int n = blockIdx.x, t = threadIdx.x;
    erow[t] = env[n * 256 + t];
    __syncthreads();
    float acc = 0.f;
#pragma unroll 8
    for (int c = 0; c < 256; ++c) acc += erow[c] * Wk[c * 256 + t];
    int h = t >> 5, d = t & 31;
    kbf[(h * N_ + n) * D_ + d] = f2bf(acc);
}

// ---- K3: q = xbf @ WqT^T via MFMA, out bf16 in (B,H,S,D), scaled ---------
// block = 256 thr = 4 waves; block covers 16 rows x 256 cols; wave w: cols w*64..
__global__ __launch_bounds__(256) void k_qproj(
        const unsigned short* __restrict__ xbf,
        const unsigned short* __restrict__ wqt,
        unsigned short* __restrict__ qws) {
    int tid  = threadIdx.x;
    int lane = tid & 63, w = tid >> 6;
    int l15  = lane & 15, quad = lane >> 4;
    int r0   = blockIdx.x * 16;
    int nb   = w * 64;

    const unsigned short* arow = xbf + (size_t)(r0 + l15) * 256 + quad * 8;
    const unsigned short* brow[4];
#pragma unroll
    for (int nt = 0; nt < 4; ++nt)
        brow[nt] = wqt + (size_t)(nb + nt * 16 + l15) * 256 + quad * 8;

    f32x4 acc[4] = {};
#pragma unroll
    for (int kk = 0; kk < 8; ++kk) {
        bf16x8 a = *(const bf16x8*)(arow + kk * 32);
#pragma unroll
        for (int nt = 0; nt < 4; ++nt) {
            bf16x8 b = *(const bf16x8*)(brow[nt] + kk * 32);
            acc[nt] = __builtin_amdgcn_mfma_f32_16x16x32_bf16(a, b, acc[nt], 0, 0, 0);
        }
    }
    // C layout: col = lane&15 (qk col), row = quad*4+reg (global row)
#pragma unroll
    for (int nt = 0; nt < 4; ++nt) {
        int col = nb + nt * 16 + l15;
        int h = col >> 5, d = col & 31;
#pragma unroll
        for (int r = 0; r < 4; ++r) {
            int gr = r0 + quad * 4 + r;
            int b = gr >> 11, s = gr & 2047;
            qws[(((size_t)(b * H_ + h)) * S_ + s) * D_ + d] = f2bf(acc[nt][r] * 0.0625f);
        }
    }
}

// ---- K4: scores + softmax + outputs --------------------------------------
// grid 2048: bh = bid>>4 (128), s-block = (bid&15)*128. 4 waves: wave w owns n in [w*128, w*128+128).
// B-frags (k) live in registers for whole block; A-frag streamed per 16-s tile.
__global__ __launch_bounds__(256) void k_scores(
        const unsigned short* __restrict__ qws,
        const unsigned short* __restrict__ kbf,
        float* __restrict__ out) {
    float* env_att = out;
    float* causal  = out + (size_t)B_ * H_ * S_;
    float* es      = out + (size_t)2 * B_ * H_ * S_;

    int tid  = threadIdx.x;
    int lane = tid & 63, w = tid >> 6;
    int l15  = lane & 15, quad = lane >> 4;

    int bid  = blockIdx.x;
    int bh   = bid >> 4;
    int sblk = (bid & 15) * 128;
    int h    = bh & 7;

    __shared__ float red[4][16];

    // load 8 B-frags: lane holds kbf[h][n= nb+j*16+l15][quad*8 .. +8)
    const unsigned short* kb = kbf + (size_t)h * N_ * D_;
    int nb = w * 128;
    bf16x8 bf[8];
#pragma unroll
    for (int j = 0; j < 8; ++j)
        bf[j] = *(const bf16x8*)(kb + (size_t)(nb + j * 16 + l15) * D_ + quad * 8);

    const unsigned short* qbase = qws + (size_t)bh * S_ * D_;

    for (int st = 0; st < 8; ++st) {
        int s0 = sblk + st * 16;
        bf16x8 a = *(const bf16x8*)(qbase + (size_t)(s0 + l15) * D_ + quad * 8);

        f32x4 c[8];
#pragma unroll
        for (int j = 0; j < 8; ++j) {
            f32x4 z = {};
            c[j] = __builtin_amdgcn_mfma_f32_16x16x32_bf16(a, bf[j], z, 0, 0, 0);
        }
        // exp (no max-subtract: |score| < ~3) + per-lane partial row sums
        float psum[4] = {0.f, 0.f, 0.f, 0.f};
#pragma unroll
        for (int j = 0; j < 8; ++j)
#pragma unroll
            for (int r = 0; r < 4; ++r) {
                float e = __expf(c[j][r]);
                c[j][r] = e;
                psum[r] += e;
            }
        // reduce across the 16 lanes of each quad (cols)
#pragma unroll
        for (int off = 1; off < 16; off <<= 1)
#pragma unroll
            for (int r = 0; r < 4; ++r)
                psum[r] += __shfl_xor(psum[r], off, 64);
        if (l15 == 0) {
#pragma unroll
            for (int r = 0; r < 4; ++r) red[w][quad * 4 + r] = psum[r];
        }
        __syncthreads();
        float inv[4];
#pragma unroll
        for (int r = 0; r < 4; ++r) {
            int row = quad * 4 + r;
            float tot = red[0][row] + red[1][row] + red[2][row] + red[3][row];
            inv[r] = 1.0f / tot;
        }
        __syncthreads();   // red reusable next iter

        int srow = bh * S_ + s0 + quad * 4;   // + r
#pragma unroll
        for (int j = 0; j < 8; ++j) {
            int n = nb + j * 16 + l15;
#pragma unroll
            for (int r = 0; r < 4; ++r) {
                float p = c[j][r] * inv[r];
                if (n > 0) es[(size_t)(srow + r) * 511 + (n - 1)] = p;
            }
        }
        if (w == 0 && l15 == 0) {
#pragma unroll
            for (int r = 0; r < 4; ++r) {
                float p0 = c[0][r] * inv[r];
                causal[srow + r]  = p0;
                env_att[srow + r] = 1.0f - p0;
            }
        }
    }
}

extern "C" void kernel_launch(void* const* d_in, const int* in_sizes, int n_in,
                              void* d_out, int out_size, void* d_ws, size_t ws_size,
                              hipStream_t stream) {
    const float* x   = (const float*)d_in[0];
    const float* env = (const float*)d_in[1];
    const float* Wq  = (const float*)d_in[2];
    const float* Wk  = (const float*)d_in[3];
    float* out = (float*)d_out;

    char* ws = (char*)d_ws;
    unsigned short* xbf = (unsigned short*)(ws);                 // 16.78 MB
    unsigned short* qws = (unsigned short*)(ws + 16777216);      // 16.78 MB
    unsigned short* kbf = (unsigned short*)(ws + 33554432);      // 256 KB
    unsigned short* wqt = (unsigned short*)(ws + 33816576);      // 128 KB

    k_convert_x<<<8192, 256, 0, stream>>>(x, xbf);
    k_wqt      <<<256,  256, 0, stream>>>(Wq, wqt);
    k_kproj    <<<512,  256, 0, stream>>>(env, Wk, kbf);
    k_qproj    <<<2048, 256, 0, stream>>>(xbf, wqt, qws);
    k_scores   <<<2048, 256, 0, stream>>>(qws, kbf, out);
}

// Round 2
// 635.453 us; speedup vs baseline: 1.0541x; 1.0541x over previous
//
#include <hip/hip_runtime.h>
#include <hip/hip_bf16.h>

// Problem constants
#define B_  16
#define S_  2048
#define C_  256
#define QK_ 256
#define H_  8
#define N_  512
#define D_  32
// SCALING = QK^-0.5 = 0.0625, folded into q projection epilogue.

typedef short  bf16x8 __attribute__((ext_vector_type(8)));
typedef float  f32x4  __attribute__((ext_vector_type(4)));

__device__ __forceinline__ unsigned short f2bf(float f) {
    union { float f; unsigned u; } v; v.f = f;
    unsigned r = v.u + 0x7fffu + ((v.u >> 16) & 1u);   // RNE
    return (unsigned short)(r >> 16);
}

// ---- K0: prep. blocks [0,256): WqT bf16 transpose; [256,768): k projection.
__global__ void k_prep(const float* __restrict__ Wq,
                       const float* __restrict__ env,
                       const float* __restrict__ Wk,
                       unsigned short* __restrict__ wqt,
                       unsigned short* __restrict__ kbf) {
    __shared__ float erow[256];
    int bid = blockIdx.x, t = threadIdx.x;
    if (bid < 256) {
        // WqT[n][c] = bf16(Wq[c][n])
        wqt[bid * 256 + t] = f2bf(Wq[t * 256 + bid]);
    } else {
        // kbf[h][n][d] = bf16( env[n,:] . Wk[:, h*32+d] )
        int n = bid - 256;
        erow[t] = env[n * 256 + t];
        __syncthreads();
        float acc = 0.f;
#pragma unroll 8
        for (int c = 0; c < 256; ++c) acc += erow[c] * Wk[c * 256 + t];
        int h = t >> 5, d = t & 31;
        kbf[(h * N_ + n) * D_ + d] = f2bf(acc);
    }
}

// ---- K1: q = x @ WqT^T via MFMA (x converted to bf16 inline), scaled -----
// block = 256 thr = 4 waves; block covers 16 rows x 256 cols; wave w: cols w*64..
__global__ __launch_bounds__(256) void k_qproj(
        const float* __restrict__ x,
        const unsigned short* __restrict__ wqt,
        unsigned short* __restrict__ qws) {
    int tid  = threadIdx.x;
    int lane = tid & 63, w = tid >> 6;
    int l15  = lane & 15, quad = lane >> 4;
    int r0   = blockIdx.x * 16;
    int nb   = w * 64;

    const float* arow = x + (size_t)(r0 + l15) * 256 + quad * 8;
    const unsigned short* brow[4];
#pragma unroll
    for (int nt = 0; nt < 4; ++nt)
        brow[nt] = wqt + (size_t)(nb + nt * 16 + l15) * 256 + quad * 8;

    f32x4 acc[4] = {};
#pragma unroll
    for (int kk = 0; kk < 8; ++kk) {
        float4 f0 = *(const float4*)(arow + kk * 32);
        float4 f1 = *(const float4*)(arow + kk * 32 + 4);
        bf16x8 a;
        a[0] = (short)f2bf(f0.x); a[1] = (short)f2bf(f0.y);
        a[2] = (short)f2bf(f0.z); a[3] = (short)f2bf(f0.w);
        a[4] = (short)f2bf(f1.x); a[5] = (short)f2bf(f1.y);
        a[6] = (short)f2bf(f1.z); a[7] = (short)f2bf(f1.w);
#pragma unroll
        for (int nt = 0; nt < 4; ++nt) {
            bf16x8 b = *(const bf16x8*)(brow[nt] + kk * 32);
            acc[nt] = __builtin_amdgcn_mfma_f32_16x16x32_bf16(a, b, acc[nt], 0, 0, 0);
        }
    }
    // C layout: col = lane&15 (qk col), row = quad*4+reg (global row)
#pragma unroll
    for (int nt = 0; nt < 4; ++nt) {
        int col = nb + nt * 16 + l15;
        int h = col >> 5, d = col & 31;
#pragma unroll
        for (int r = 0; r < 4; ++r) {
            int gr = r0 + quad * 4 + r;
            int b = gr >> 11, s = gr & 2047;
            qws[(((size_t)(b * H_ + h)) * S_ + s) * D_ + d] = f2bf(acc[nt][r] * 0.0625f);
        }
    }
}

// ---- K2: scores + softmax + outputs --------------------------------------
// grid 2048: bh = bid>>4 (128), s-block = (bid&15)*128. 4 waves: wave w owns
// n in [w*128, w*128+128). Probs staged through padded LDS tile, then written
// out as flat, fully-coalesced 1KB dword sweeps (the 16x511 region of one
// s-tile is contiguous in es).
#define PADW 514   // 512 cols + 2 pad: quad stride 4*514 % 32 = 8 -> 2-way max
__global__ __launch_bounds__(256) void k_scores(
        const unsigned short* __restrict__ qws,
        const unsigned short* __restrict__ kbf,
        float* __restrict__ out) {
    float* env_att = out;
    float* causal  = out + (size_t)B_ * H_ * S_;
    float* es      = out + (size_t)2 * B_ * H_ * S_;

    __shared__ float red[4][16];
    __shared__ float tile[16 * PADW];

    int tid  = threadIdx.x;
    int lane = tid & 63, w = tid >> 6;
    int l15  = lane & 15, quad = lane >> 4;

    int bid  = blockIdx.x;
    int bh   = bid >> 4;
    int sblk = (bid & 15) * 128;
    int h    = bh & 7;

    // load 8 B-frags: lane holds kbf[h][n = nb+j*16+l15][quad*8 .. +8)
    const unsigned short* kb = kbf + (size_t)h * N_ * D_;
    int nb = w * 128;
    bf16x8 bf[8];
#pragma unroll
    for (int j = 0; j < 8; ++j)
        bf[j] = *(const bf16x8*)(kb + (size_t)(nb + j * 16 + l15) * D_ + quad * 8);

    const unsigned short* qbase = qws + (size_t)bh * S_ * D_;

    for (int st = 0; st < 8; ++st) {
        int s0 = sblk + st * 16;
        bf16x8 a = *(const bf16x8*)(qbase + (size_t)(s0 + l15) * D_ + quad * 8);

        f32x4 c[8];
#pragma unroll
        for (int j = 0; j < 8; ++j) {
            f32x4 z = {};
            c[j] = __builtin_amdgcn_mfma_f32_16x16x32_bf16(a, bf[j], z, 0, 0, 0);
        }
        // exp (no max-subtract: |score| < ~3) + per-lane partial row sums
        float psum[4] = {0.f, 0.f, 0.f, 0.f};
#pragma unroll
        for (int j = 0; j < 8; ++j)
#pragma unroll
            for (int r = 0; r < 4; ++r) {
                float e = __expf(c[j][r]);
                c[j][r] = e;
                psum[r] += e;
            }
        // reduce across the 16 lanes of each quad (cols)
#pragma unroll
        for (int off = 1; off < 16; off <<= 1)
#pragma unroll
            for (int r = 0; r < 4; ++r)
                psum[r] += __shfl_xor(psum[r], off, 64);
        if (l15 == 0) {
#pragma unroll
            for (int r = 0; r < 4; ++r) red[w][quad * 4 + r] = psum[r];
        }
        __syncthreads();                       // [A] red ready; tile reusable
        float inv[4];
#pragma unroll
        for (int r = 0; r < 4; ++r) {
            int row = quad * 4 + r;
            float tot = red[0][row] + red[1][row] + red[2][row] + red[3][row];
            inv[r] = 1.0f / tot;
        }
        // stage normalized probs into LDS at col n (col 0 unused by writeout)
#pragma unroll
        for (int j = 0; j < 8; ++j) {
            int n = nb + j * 16 + l15;
#pragma unroll
            for (int r = 0; r < 4; ++r)
                tile[(quad * 4 + r) * PADW + n] = c[j][r] * inv[r];
        }
        if (w == 0 && l15 == 0) {
            int srow = bh * S_ + s0 + quad * 4;
#pragma unroll
            for (int r = 0; r < 4; ++r) {
                float p0 = c[0][r] * inv[r];
                causal[srow + r]  = p0;
                env_att[srow + r] = 1.0f - p0;
            }
        }
        __syncthreads();                       // [B] tile ready
        // flat coalesced write-out: 16 rows x 511 floats, contiguous in es
        size_t region = ((size_t)bh * S_ + s0) * 511;
#pragma unroll
        for (int row = 0; row < 16; ++row) {
            es[region + row * 511 + tid] = tile[row * PADW + 1 + tid];
            if (tid < 255)
                es[region + row * 511 + 256 + tid] = tile[row * PADW + 257 + tid];
        }
    }
}

extern "C" void kernel_launch(void* const* d_in, const int* in_sizes, int n_in,
                              void* d_out, int out_size, void* d_ws, size_t ws_size,
                              hipStream_t stream) {
    const float* x   = (const float*)d_in[0];
    const float* env = (const float*)d_in[1];
    const float* Wq  = (const float*)d_in[2];
    const float* Wk  = (const float*)d_in[3];
    float* out = (float*)d_out;

    char* ws = (char*)d_ws;
    unsigned short* qws = (unsigned short*)(ws);                 // 16.78 MB
    unsigned short* kbf = (unsigned short*)(ws + 16777216);      // 256 KB
    unsigned short* wqt = (unsigned short*)(ws + 17039360);      // 128 KB

    k_prep  <<<768,  256, 0, stream>>>(Wq, env, Wk, wqt, kbf);
    k_qproj <<<2048, 256, 0, stream>>>(x, wqt, qws);
    k_scores<<<2048, 256, 0, stream>>>(qws, kbf, out);
}